// Round 3
// baseline (659.176 us; speedup 1.0000x reference)
//
#include <hip/hip_runtime.h>
#include <hip/hip_bf16.h>

// Sizes
#define NBATCH 128   // conv channels (o and c dims)
#define NSLIDE 256   // s dim (GEMM M total)
#define NSLOT  33    // conv slots: h1: k*3+p (0..17), h2: 18+2k+p, h3: 28+k
#define CCHUNKS 8
#define CPER    16                   // channels per cc chunk
#define BK      64                   // k columns staged per iteration
#define NIT     ((CPER * 128) / BK)  // 32 tile-iterations per (a, cc)
#define SLOT_ELEMS (NSLIDE * NBATCH)         // 32768
#define CC_STRIDE  (NSLOT * SLOT_ELEMS)      // floats per cc partial

using ushort8 = __attribute__((ext_vector_type(8))) unsigned short;
using bf16x8  = __attribute__((ext_vector_type(8))) __bf16;
using floatx4 = __attribute__((ext_vector_type(4))) float;

// 33 slot-wgs, ordered heavy-first (h=3, then h=2, then h=1) so the 3x-work
// wgs start earliest. Each slot (h,k,p) sums a=0..h-1 of A_{p+a} * W_h[k,:,:,a,:]^T
// internally -> exactly ONE wg owns each (slot, m_half, cc) partial (no races).
__device__ __constant__ unsigned char S_H[NSLOT] = {
  2,2,2,2,2,
  1,1,1,1,1,1,1,1,1,1,
  0,0,0,0,0,0,0,0,0,0,0,0,0,0,0,0,0,0};
__device__ __constant__ unsigned char S_K[NSLOT] = {
  0,1,2,3,4,
  0,0,1,1,2,2,3,3,4,4,
  0,0,0,1,1,1,2,2,2,3,3,3,4,4,4,5,5,5};
__device__ __constant__ unsigned char S_P[NSLOT] = {
  0,0,0,0,0,
  0,1,0,1,0,1,0,1,0,1,
  0,1,2,0,1,2,0,1,2,0,1,2,0,1,2,0,1,2};
__device__ __constant__ unsigned char S_SLOT[NSLOT] = {
  28,29,30,31,32,
  18,19,20,21,22,23,24,25,26,27,
  0,1,2,3,4,5,6,7,8,9,10,11,12,13,14,15,16,17};

__device__ __forceinline__ unsigned short f2bf(float f) {
  union { float f; unsigned u; } v; v.f = f;
  unsigned r = v.u + 0x7fffu + ((v.u >> 16) & 1u);  // RNE (inputs finite)
  return (unsigned short)(r >> 16);
}

__device__ __forceinline__ ushort8 pack8(const float4& a, const float4& b) {
  ushort8 p = { f2bf(a.x), f2bf(a.y), f2bf(a.z), f2bf(a.w),
                f2bf(b.x), f2bf(b.y), f2bf(b.z), f2bf(b.w) };
  return p;
}

__global__ __launch_bounds__(256, 2) void gemm_slots(
    const float* __restrict__ Ec,
    const float* __restrict__ W1, const float* __restrict__ W2,
    const float* __restrict__ W3,
    float* __restrict__ part)
{
  const int bx     = blockIdx.x;       // 0..65 = sidx*2 + m_half
  const int cc     = blockIdx.y;       // 0..7
  const int sidx   = bx >> 1;
  const int m_half = bx & 1;

  const int h_idx = S_H[sidx];
  const int kker  = S_K[sidx];
  const int p     = S_P[sidx];
  const int slot  = S_SLOT[sidx];
  const int h     = h_idx + 1;

  const float* wbase = (h_idx == 0) ? W1 : ((h_idx == 1) ? W2 : W3);
  const long o_stride = 16384L * h;    // W element stride over o
  const long c_stride = 128L * h;      // W element stride over c
  const float* wk = wbase + (long)kker * (128L * o_stride);
  const int c0 = cc * CPER;
  const int NT = h * NIT;              // 32 / 64 / 96 total tile iterations

  // LDS: bf16 tiles 128 rows x 64 k, XOR-swizzled in 8-short groups, no pad.
  __shared__ __align__(16) unsigned short As[128 * 64];
  __shared__ __align__(16) unsigned short Bs[128 * 64];

  const int tid = threadIdx.x;
  const int c8  = tid & 7;             // col group: floats c8*8 .. c8*8+7
  const int rb  = tid >> 3;            // 0..31, rows rb + 32q
  const int swz = ((c8 ^ (rb & 7)) << 3);   // swizzled LDS col offset (shorts)

  // staging base pointers (row rb, col group c8); tile t adds a/itv offsets
  const float* aP = Ec + (long)p * 128 + (long)(m_half * 128 + rb) * 384
                    + c8 * 8 + (long)c0 * 98304;
  const float* wP = wk + (long)rb * o_stride + c8 * 8 + (long)c0 * c_stride;

  const int wave = tid >> 6;
  const int lane = tid & 63;
  const int wm = (wave >> 1) * 64;
  const int wn = (wave & 1) * 64;
  const int lr = lane & 15;
  const int lq = lane >> 4;

  floatx4 acc[4][4];
#pragma unroll
  for (int i = 0; i < 4; ++i)
#pragma unroll
    for (int j = 0; j < 4; ++j) acc[i][j] = (floatx4){0.f, 0.f, 0.f, 0.f};

  float4 aL[8], wL[8];

  // tile t: a = t>>5 (conv row within kernel), itv = t&31 (k-slice within chunk)
#define LOAD_TILE(t_)                                                           \
  {                                                                             \
    const int tv  = (t_);                                                       \
    const int av  = tv >> 5;                                                    \
    const int itv = tv & 31;                                                    \
    const long aOff = (long)av * 128 + (long)(itv >> 1) * 98304                 \
                      + (long)(itv & 1) * 64;                                   \
    const long bOff = (long)av * 128 + (long)(itv >> 1) * c_stride              \
                      + (long)(itv & 1) * 64;                                   \
    _Pragma("unroll")                                                           \
    for (int q = 0; q < 4; ++q) {                                               \
      const float* ap = aP + aOff + (long)q * (32 * 384);                       \
      const float* bp = wP + bOff + (long)q * 32 * o_stride;                    \
      aL[2 * q]     = *reinterpret_cast<const float4*>(ap);                     \
      aL[2 * q + 1] = *reinterpret_cast<const float4*>(ap + 4);                 \
      wL[2 * q]     = *reinterpret_cast<const float4*>(bp);                     \
      wL[2 * q + 1] = *reinterpret_cast<const float4*>(bp + 4);                 \
    }                                                                           \
  }

  LOAD_TILE(0);

  for (int t = 0; t < NT; ++t) {
    // convert + swizzled LDS store
#pragma unroll
    for (int q = 0; q < 4; ++q) {
      const int row = rb + 32 * q;
      *reinterpret_cast<ushort8*>(&As[row * 64 + swz]) = pack8(aL[2*q], aL[2*q+1]);
      *reinterpret_cast<ushort8*>(&Bs[row * 64 + swz]) = pack8(wL[2*q], wL[2*q+1]);
    }
    __syncthreads();

    if (t + 1 < NT) LOAD_TILE(t + 1);   // prefetch, hidden under MFMAs

#pragma unroll
    for (int ks = 0; ks < 2; ++ks) {
      bf16x8 af[4], bf_[4];
#pragma unroll
      for (int i = 0; i < 4; ++i) {
        const int row = wm + 16 * i + lr;
        const int col = (((ks * 4 + lq) ^ (lr & 7)) << 3);
        af[i] = *reinterpret_cast<const bf16x8*>(&As[row * 64 + col]);
      }
#pragma unroll
      for (int j = 0; j < 4; ++j) {
        const int row = wn + 16 * j + lr;
        const int col = (((ks * 4 + lq) ^ (lr & 7)) << 3);
        bf_[j] = *reinterpret_cast<const bf16x8*>(&Bs[row * 64 + col]);
      }
#pragma unroll
      for (int i = 0; i < 4; ++i)
#pragma unroll
        for (int j = 0; j < 4; ++j)
          acc[i][j] = __builtin_amdgcn_mfma_f32_16x16x32_bf16(af[i], bf_[j], acc[i][j], 0, 0, 0);
    }
    __syncthreads();   // LDS reads done before next overwrite
  }
#undef LOAD_TILE

  // non-atomic partial store: part[cc][slot][s][o]  (D layout: row = lq*4+r, col = lr)
  float* base = part + ((long)cc * NSLOT + slot) * SLOT_ELEMS;
#pragma unroll
  for (int i = 0; i < 4; ++i) {
#pragma unroll
    for (int j = 0; j < 4; ++j) {
#pragma unroll
      for (int r = 0; r < 4; ++r) {
        int s = m_half * 128 + wm + 16 * i + lq * 4 + r;
        int o = wn + 16 * j + lr;
        base[s * NBATCH + o] = acc[i][j][r];
      }
    }
  }
}

__global__ void epilogue(const float* __restrict__ part,
                         const float* __restrict__ b1, const float* __restrict__ b2,
                         const float* __restrict__ b3, float* __restrict__ out)
{
  int t = blockIdx.x * 256 + threadIdx.x;   // 32768 threads: (s,o)
  int o = t & 127;
  int s = t >> 7;
  const float* base = part + s * NBATCH + o;

  float v[NSLOT];
#pragma unroll
  for (int sl = 0; sl < NSLOT; ++sl) {
    float a = 0.f;
#pragma unroll
    for (int cc = 0; cc < CCHUNKS; ++cc)
      a += base[(long)cc * CC_STRIDE + sl * SLOT_ELEMS];
    v[sl] = a;
  }

  float r[16];
#pragma unroll
  for (int k = 0; k < 6; ++k) {   // h=1, kernels 3k
    float m = fmaxf(fmaxf(v[3 * k + 0], v[3 * k + 1]), v[3 * k + 2]);
    r[3 * k + 0] = fmaxf(m + b1[k * 128 + o], 0.f);
  }
#pragma unroll
  for (int k = 0; k < 5; ++k) {   // h=2, kernels 3k+1
    float m = fmaxf(v[18 + 2 * k], v[18 + 2 * k + 1]);
    r[3 * k + 1] = fmaxf(m + b2[k * 128 + o], 0.f);
  }
#pragma unroll
  for (int k = 0; k < 5; ++k) {   // h=3, kernels 3k+2
    r[3 * k + 2] = fmaxf(v[28 + k] + b3[k * 128 + o], 0.f);
  }
  float* op = out + ((long)o * 256 + s) * 16;   // out[B][S][1][K]
  reinterpret_cast<float4*>(op)[0] = make_float4(r[0], r[1], r[2], r[3]);
  reinterpret_cast<float4*>(op)[1] = make_float4(r[4], r[5], r[6], r[7]);
  reinterpret_cast<float4*>(op)[2] = make_float4(r[8], r[9], r[10], r[11]);
  reinterpret_cast<float4*>(op)[3] = make_float4(r[12], r[13], r[14], r[15]);
}

extern "C" void kernel_launch(void* const* d_in, const int* in_sizes, int n_in,
                              void* d_out, int out_size, void* d_ws, size_t ws_size,
                              hipStream_t stream) {
  const float* Ec = (const float*)d_in[0];
  const float* W1 = (const float*)d_in[1];
  const float* W2 = (const float*)d_in[2];
  const float* W3 = (const float*)d_in[3];
  const float* b1 = (const float*)d_in[4];
  const float* b2 = (const float*)d_in[5];
  const float* b3 = (const float*)d_in[6];
  float* out  = (float*)d_out;
  float* part = (float*)d_ws;   // 8 * 33 * 256 * 128 floats = 34.6 MB, fully overwritten

  gemm_slots<<<dim3(66, CCHUNKS), 256, 0, stream>>>(Ec, W1, W2, W3, part);
  epilogue<<<(NSLIDE * NBATCH) / 256, 256, 0, stream>>>(part, b1, b2, b3, out);
}

// Round 4
// 410.711 us; speedup vs baseline: 1.6050x; 1.6050x over previous
//
#include <hip/hip_runtime.h>
#include <hip/hip_bf16.h>

// Sizes
#define NBATCH 128   // conv channels (o dim)
#define NSLIDE 256   // s dim
#define PART_ELEMS 32768          // 256 s x 128 o per partial unit
#define NPART 424                 // h1:18*8 + h2:10*16 + h3:5*24
// partial bf16: 424 * 32768 * 2 B = 27.75 MB (< 34.6 MB proven ws)

using ushort4v = __attribute__((ext_vector_type(4))) unsigned short;
using bf16x8   = __attribute__((ext_vector_type(8))) __bf16;
using floatx4  = __attribute__((ext_vector_type(4))) float;

__device__ __forceinline__ unsigned short f2bf(float f) {
  union { float f; unsigned u; } v; v.f = f;
  unsigned r = v.u + 0x7fffu + ((v.u >> 16) & 1u);  // RNE (inputs finite)
  return (unsigned short)(r >> 16);
}
__device__ __forceinline__ ushort4v pack4(const float4& a) {
  ushort4v p = { f2bf(a.x), f2bf(a.y), f2bf(a.z), f2bf(a.w) };
  return p;
}

// 848 wgs, each: one (h,k,a,ch, p, m_half), exactly 32 iterations of 128x128x64.
// Members sharing the same W chunk are CONSECUTIVE in blockIdx.x:
//   h1: bx in [0,288):   group g = bx/6  (k=g>>3, ch=g&7, a=0),  mem: p=mem>>1, m=mem&1
//   h2: bx in [288,608): t=bx-288, g=t>>2 (k=g>>4, a=(g>>3)&1, ch=g&7), mem: p,m
//   h3: bx in [608,848): t=bx-608, g=t>>1 (k=g/24, a=(g%24)>>3, ch=g&7), p=0, m=t&1
__global__ __launch_bounds__(256, 3) void gemm_uniform(
    const float* __restrict__ Ec,
    const float* __restrict__ W1, const float* __restrict__ W2,
    const float* __restrict__ W3,
    unsigned short* __restrict__ part)
{
  const int bx = blockIdx.x;
  int htype, k, a, ch, p, m;
  if (bx < 288) {
    htype = 0; int g = bx / 6, mem = bx - g * 6;
    k = g >> 3; ch = g & 7; a = 0; p = mem >> 1; m = mem & 1;
  } else if (bx < 608) {
    htype = 1; int t = bx - 288; int g = t >> 2, mem = t & 3;
    k = g >> 4; a = (g >> 3) & 1; ch = g & 7; p = mem >> 1; m = mem & 1;
  } else {
    htype = 2; int t = bx - 608; int g = t >> 1;
    k = g / 24; int r24 = g - k * 24; a = r24 >> 3; ch = r24 & 7; p = 0; m = t & 1;
  }
  const int l = p + a;                  // Ec height index
  const int h = htype + 1;
  const float* wbase = (htype == 0) ? W1 : ((htype == 1) ? W2 : W3);
  const long o_stride = 16384L * h;     // W element stride over o
  const long c_stride = 128L * h;       // W element stride over c

  // partial unit index (one owner per (slot, a, ch); m-halves write disjoint rows)
  int slot, seq;
  if (htype == 0)      { slot = 3 * k + p;      seq = ch; }
  else if (htype == 1) { slot = 18 + 2 * k + p; seq = a * 8 + ch; }
  else                 { slot = 28 + k;         seq = a * 8 + ch; }
  int pbase;
  if (slot < 18)      pbase = slot * 8;
  else if (slot < 28) pbase = 144 + (slot - 18) * 16;
  else                pbase = 304 + (slot - 28) * 24;
  const int pslot = pbase + seq;

  // LDS: bf16 tiles 128 rows x 64 k, XOR-swizzled in 16 B granules (verified r3).
  __shared__ __align__(16) unsigned short As[128 * 64];
  __shared__ __align__(16) unsigned short Bs[128 * 64];

  const int tid = threadIdx.x;
  const int c16 = tid & 15;            // 16 lanes x 16 B = 256 B dense per row
  const int r0  = tid >> 4;            // rows r0 + 16q
  // LDS store offset pieces: granule gh = c16>>1, half = c16&1
  const int gh   = c16 >> 1;
  const int half4 = (c16 & 1) * 4;     // short offset within granule

  const float* aP = Ec + (long)l * 128 + (long)(m * 128 + r0) * 384 + c16 * 4;
  const float* wP = wbase + (long)k * 128 * o_stride + (long)a * 128
                    + (long)r0 * o_stride + c16 * 4;

  const int wave = tid >> 6;
  const int lane = tid & 63;
  const int wm = (wave >> 1) * 64;
  const int wn = (wave & 1) * 64;
  const int lr = lane & 15;
  const int lq = lane >> 4;

  floatx4 acc[4][4];
#pragma unroll
  for (int i = 0; i < 4; ++i)
#pragma unroll
    for (int j = 0; j < 4; ++j) acc[i][j] = (floatx4){0.f, 0.f, 0.f, 0.f};

  float4 aL[8], wL[8];

  // iteration t in [0,32): c = ch*16 + (t>>1), d-half = t&1
#define LOAD_TILE(t_)                                                           \
  {                                                                             \
    const int tv = (t_);                                                        \
    const long cA = (long)(ch * 16 + (tv >> 1)) * 98304 + (long)(tv & 1) * 64;  \
    const long cB = (long)(ch * 16 + (tv >> 1)) * c_stride + (long)(tv & 1) * 64;\
    _Pragma("unroll")                                                           \
    for (int q = 0; q < 8; ++q) {                                               \
      aL[q] = *reinterpret_cast<const float4*>(aP + cA + (long)q * (16 * 384)); \
      wL[q] = *reinterpret_cast<const float4*>(wP + cB + (long)q * 16 * o_stride);\
    }                                                                           \
  }

  LOAD_TILE(0);

  for (int t = 0; t < 32; ++t) {
    // convert + swizzled LDS store: row = r0+16q; granule g' = gh ^ (row&7)
#pragma unroll
    for (int q = 0; q < 8; ++q) {
      const int row = r0 + 16 * q;
      const int off = row * 64 + ((gh ^ (row & 7)) << 3) + half4;
      *reinterpret_cast<ushort4v*>(&As[off]) = pack4(aL[q]);
      *reinterpret_cast<ushort4v*>(&Bs[off]) = pack4(wL[q]);
    }
    __syncthreads();

    if (t + 1 < 32) LOAD_TILE(t + 1);   // prefetch, hidden under MFMAs

#pragma unroll
    for (int ks = 0; ks < 2; ++ks) {
      bf16x8 af[4], bf_[4];
#pragma unroll
      for (int i = 0; i < 4; ++i) {
        const int row = wm + 16 * i + lr;
        const int col = (((ks * 4 + lq) ^ (row & 7)) << 3);
        af[i] = *reinterpret_cast<const bf16x8*>(&As[row * 64 + col]);
      }
#pragma unroll
      for (int j = 0; j < 4; ++j) {
        const int row = wn + 16 * j + lr;
        const int col = (((ks * 4 + lq) ^ (row & 7)) << 3);
        bf_[j] = *reinterpret_cast<const bf16x8*>(&Bs[row * 64 + col]);
      }
#pragma unroll
      for (int i = 0; i < 4; ++i)
#pragma unroll
        for (int j = 0; j < 4; ++j)
          acc[i][j] = __builtin_amdgcn_mfma_f32_16x16x32_bf16(af[i], bf_[j], acc[i][j], 0, 0, 0);
    }
    __syncthreads();
  }
#undef LOAD_TILE

  // bf16 partial store (D layout: row = lq*4+r, col = lr); m-half picks row block
  unsigned short* base = part + (long)pslot * PART_ELEMS + (long)m * 128 * NBATCH;
#pragma unroll
  for (int i = 0; i < 4; ++i) {
#pragma unroll
    for (int j = 0; j < 4; ++j) {
#pragma unroll
      for (int r = 0; r < 4; ++r) {
        int s = wm + 16 * i + lq * 4 + r;
        int o = wn + 16 * j + lr;
        base[s * NBATCH + o] = f2bf(acc[i][j][r]);
      }
    }
  }
}

__device__ __forceinline__ float bf2f(unsigned short u) {
  union { unsigned u; float f; } v; v.u = ((unsigned)u) << 16; return v.f;
}

__global__ void epilogue(const unsigned short* __restrict__ part,
                         const float* __restrict__ b1, const float* __restrict__ b2,
                         const float* __restrict__ b3, float* __restrict__ out)
{
  int t = blockIdx.x * 256 + threadIdx.x;   // 32768 threads: (s,o)
  int o = t & 127;
  int s = t >> 7;
  const long idx = (long)s * NBATCH + o;

  float v[33];
#pragma unroll
  for (int sl = 0; sl < 18; ++sl) {          // h1: 8 partials each
    float a = 0.f;
#pragma unroll
    for (int c = 0; c < 8; ++c) a += bf2f(part[(long)(sl * 8 + c) * PART_ELEMS + idx]);
    v[sl] = a;
  }
#pragma unroll
  for (int sl = 0; sl < 10; ++sl) {          // h2: 16 partials each
    float a = 0.f;
#pragma unroll
    for (int c = 0; c < 16; ++c) a += bf2f(part[(long)(144 + sl * 16 + c) * PART_ELEMS + idx]);
    v[18 + sl] = a;
  }
#pragma unroll
  for (int sl = 0; sl < 5; ++sl) {           // h3: 24 partials each
    float a = 0.f;
#pragma unroll
    for (int c = 0; c < 24; ++c) a += bf2f(part[(long)(304 + sl * 24 + c) * PART_ELEMS + idx]);
    v[28 + sl] = a;
  }

  float r[16];
#pragma unroll
  for (int k = 0; k < 6; ++k) {   // h=1, kernels 3k
    float mx = fmaxf(fmaxf(v[3 * k + 0], v[3 * k + 1]), v[3 * k + 2]);
    r[3 * k + 0] = fmaxf(mx + b1[k * 128 + o], 0.f);
  }
#pragma unroll
  for (int k = 0; k < 5; ++k) {   // h=2, kernels 3k+1
    float mx = fmaxf(v[18 + 2 * k], v[18 + 2 * k + 1]);
    r[3 * k + 1] = fmaxf(mx + b2[k * 128 + o], 0.f);
  }
#pragma unroll
  for (int k = 0; k < 5; ++k) {   // h=3, kernels 3k+2
    r[3 * k + 2] = fmaxf(v[28 + k] + b3[k * 128 + o], 0.f);
  }
  float* op = out + ((long)o * 256 + s) * 16;   // out[B][S][1][K]
  reinterpret_cast<float4*>(op)[0] = make_float4(r[0], r[1], r[2], r[3]);
  reinterpret_cast<float4*>(op)[1] = make_float4(r[4], r[5], r[6], r[7]);
  reinterpret_cast<float4*>(op)[2] = make_float4(r[8], r[9], r[10], r[11]);
  reinterpret_cast<float4*>(op)[3] = make_float4(r[12], r[13], r[14], r[15]);
}

extern "C" void kernel_launch(void* const* d_in, const int* in_sizes, int n_in,
                              void* d_out, int out_size, void* d_ws, size_t ws_size,
                              hipStream_t stream) {
  const float* Ec = (const float*)d_in[0];
  const float* W1 = (const float*)d_in[1];
  const float* W2 = (const float*)d_in[2];
  const float* W3 = (const float*)d_in[3];
  const float* b1 = (const float*)d_in[4];
  const float* b2 = (const float*)d_in[5];
  const float* b3 = (const float*)d_in[6];
  float* out = (float*)d_out;
  unsigned short* part = (unsigned short*)d_ws;   // 27.75 MB bf16, fully overwritten

  gemm_uniform<<<848, 256, 0, stream>>>(Ec, W1, W2, W3, part);
  epilogue<<<(NSLIDE * NBATCH) / 256, 256, 0, stream>>>(part, b1, b2, b3, out);
}